// Round 10
// baseline (1659.907 us; speedup 1.0000x reference)
//
#include <hip/hip_runtime.h>
#include <hip/hip_bf16.h>
#include <float.h>

#define D 64
#define K 512
#define HW 1024
#define DHW (D * HW)
#define N_PTS 65536
#define OUT_ELEMS (64 * D * HW)     /* 4,194,304 */
#define LOSS_OFF OUT_ELEMS
#define IDX_OFF (OUT_ELEMS + 1)
#define PTS_PER_BLOCK 64
#define NBLOCKS (N_PTS / PTS_PER_BLOCK)   /* 1024 */
#define TAU 4.0e-5f   /* residual (~6e-6) + numpy fp32 quant band, 4x slack */

typedef unsigned short ushort_t;
typedef unsigned long long ull_t;
typedef __attribute__((ext_vector_type(8))) short bf16x8;
typedef __attribute__((ext_vector_type(4))) float f32x4;

union U16x8 { uint4 u; bf16x8 v; ushort_t s[8]; };

__device__ __forceinline__ ushort_t f2bf(float v) {
    __hip_bfloat16 h = __float2bfloat16(v);
    return *reinterpret_cast<ushort_t*>(&h);
}
__device__ __forceinline__ float bf2f(ushort_t u) {
    unsigned int x = ((unsigned int)u) << 16;
    return *reinterpret_cast<float*>(&x);
}
__device__ __forceinline__ unsigned int f2ord(float s) {
    unsigned int u = __float_as_uint(s);
    return (u & 0x80000000u) ? ~u : (u | 0x80000000u);
}
__device__ __forceinline__ ull_t shfl_xor_u64(ull_t v, int mask) {
    unsigned int lo = (unsigned int)v, hi = (unsigned int)(v >> 32);
    lo = __shfl_xor((int)lo, mask);
    hi = __shfl_xor((int)hi, mask);
    return ((ull_t)hi << 32) | (ull_t)lo;
}

// ---------------------------------------------------------------------------
// numpy pairwise-sum (n=64): 8 accumulators over squares, combined
// ((r0+r1)+(r2+r3))+((r4+r5)+(r6+r7)); all adds/muls un-contracted.
// ---------------------------------------------------------------------------
__device__ __forceinline__ float np_sumsq64(const float* v) {
    float r[8];
#pragma unroll
    for (int j = 0; j < 8; ++j) r[j] = __fmul_rn(v[j], v[j]);
#pragma unroll
    for (int i = 8; i < D; i += 8) {
#pragma unroll
        for (int j = 0; j < 8; ++j)
            r[j] = __fadd_rn(r[j], __fmul_rn(v[i + j], v[i + j]));
    }
    return __fadd_rn(
        __fadd_rn(__fadd_rn(r[0], r[1]), __fadd_rn(r[2], r[3])),
        __fadd_rn(__fadd_rn(r[4], r[5]), __fadd_rn(r[6], r[7])));
}

// ---------------------------------------------------------------------------
// Prep (8 blocks x 64): thread = code k. e2 (numpy order), bhi/blo fragments
// (layout verified r6): idx = kh*2048 + (k>>4)*64 + g*16 + (k&15).
// ---------------------------------------------------------------------------
__global__ void vq_prep_kernel(const float* __restrict__ cb,
                               float* __restrict__ e2,
                               uint4* __restrict__ bhi,
                               uint4* __restrict__ blo) {
    const int k = blockIdx.x * 64 + threadIdx.x;
    float row[D];
#pragma unroll
    for (int d = 0; d < D; ++d) row[d] = cb[k * D + d];
    e2[k] = np_sumsq64(row);
#pragma unroll
    for (int kh = 0; kh < 2; ++kh) {
#pragma unroll
        for (int g = 0; g < 4; ++g) {
            U16x8 hi, lo;
#pragma unroll
            for (int i = 0; i < 8; ++i) {
                float v = row[kh * 32 + g * 8 + i];
                ushort_t h = f2bf(v);
                hi.s[i] = h;
                lo.s[i] = f2bf(__fsub_rn(v, bf2f(h)));
            }
            const int gid = kh * 2048 + (k >> 4) * 64 + g * 16 + (k & 15);
            bhi[gid] = hi.u;
            blo[gid] = lo.u;
        }
    }
}

// ---------------------------------------------------------------------------
// Main VQ. Block = 64 points, 4 waves; wave w owns points [w*16, w*16+16)
// against ALL 512 codes (2 chunks of 256 reusing one c[16] accumulator).
// 3 MFMA passes (xh.eh + xl.eh + xh.el): |C - x.e| <= ~6e-6 << fp32 ulp@64.
// Decision: per-lane online (max, band-count, band-min-code) with TAU band —
// never undercounts (any elem within TAU of the final max is within TAU of
// every running max) — merged with order-invariant fmax/add/min shuffles.
// cnt==1 -> unique argmin. Else wave-local exact 512-scan with the bit-exact
// numpy chain (validated r2-r8), min-key reduced. No atomics anywhere:
// bit-deterministic across replays by construction (r8 lesson).
// ---------------------------------------------------------------------------
__global__ __launch_bounds__(256, 4) void vq_main_kernel(
        const float* __restrict__ z, const float* __restrict__ cb,
        const float* __restrict__ e2, const uint4* __restrict__ bhi,
        const uint4* __restrict__ blo, float* __restrict__ out,
        float* __restrict__ partial) {
    __shared__ float x_lds[D][65];          // pad 65: conflict-free
    __shared__ float q_lds[D][65];          // gathered codebook rows
    __shared__ float e2_lds[K];
    __shared__ int   ids[64];
    __shared__ int   need[64];
    __shared__ float wsum[4];

    const int t   = threadIdx.x;
    const int l   = t & 63;
    const int w   = t >> 6;
    const int p0  = w * 16;                 // this wave's 16 points
    const int n0  = blockIdx.x * PTS_PER_BLOCK;
    const int b   = n0 >> 10;
    const int hw0 = n0 & 1023;

    // ---- stage x (coalesced), e2, init ----
    const float* zb = z + b * DHW + hw0;
#pragma unroll
    for (int i = 0; i < 16; ++i) {
        const int d = w * 16 + i;
        x_lds[d][l] = zb[d * HW + l];
    }
    e2_lds[t]       = e2[t];
    e2_lds[t + 256] = e2[t + 256];
    if (t < 64) need[t] = 0;
    __syncthreads();

    // ---- A fragments (hi + exact lo residual), layout verified r6 ----
    bf16x8 ah[2], al[2];
#pragma unroll
    for (int kh = 0; kh < 2; ++kh) {
        const int pt = p0 + (l & 15);
        const int d0 = kh * 32 + ((l >> 4) << 3);
        U16x8 uh, ul;
#pragma unroll
        for (int i = 0; i < 8; ++i) {
            float v = x_lds[d0 + i][pt];
            ushort_t h = f2bf(v);
            uh.s[i] = h;
            ul.s[i] = f2bf(__fsub_rn(v, bf2f(h)));
        }
        ah[kh] = uh.v;
        al[kh] = ul.v;
    }

    // ---- per-lane online decision state (4 rows: r=0..3) ----
    float mx[4];
    int   cnt[4], mn[4];
#pragma unroll
    for (int r = 0; r < 4; ++r) { mx[r] = -FLT_MAX; cnt[r] = 0; mn[r] = 0x7fffffff; }

    for (int chunk = 0; chunk < 2; ++chunk) {
        // ---- MFMA: c[nt] = (xh+xl).eh + xh.el for 16 code-tiles ----
        f32x4 c[16];
#pragma unroll
        for (int nt = 0; nt < 16; ++nt) c[nt] = (f32x4){0.f, 0.f, 0.f, 0.f};
#pragma unroll
        for (int kh = 0; kh < 2; ++kh) {
            const int base = kh * 2048 + chunk * 1024;
#pragma unroll
            for (int nt = 0; nt < 16; ++nt) {
                U16x8 bu; bu.u = bhi[base + nt * 64 + l];
                c[nt] = __builtin_amdgcn_mfma_f32_16x16x32_bf16(ah[kh], bu.v, c[nt], 0, 0, 0);
                c[nt] = __builtin_amdgcn_mfma_f32_16x16x32_bf16(al[kh], bu.v, c[nt], 0, 0, 0);
            }
        }
#pragma unroll
        for (int kh = 0; kh < 2; ++kh) {
            const int base = kh * 2048 + chunk * 1024;
#pragma unroll
            for (int nt = 0; nt < 16; ++nt) {
                U16x8 bl; bl.u = blo[base + nt * 64 + l];
                c[nt] = __builtin_amdgcn_mfma_f32_16x16x32_bf16(ah[kh], bl.v, c[nt], 0, 0, 0);
            }
        }
        // ---- score + online update (deterministic program order) ----
#pragma unroll
        for (int nt = 0; nt < 16; ++nt) {
            const int code = chunk * 256 + nt * 16 + (l & 15);
            const float B = e2_lds[code];
#pragma unroll
            for (int r = 0; r < 4; ++r) {
                const float s = __builtin_fmaf(B, -0.5f, c[nt][r]);
                if (s > mx[r]) mx[r] = s;
                if (s >= mx[r] - TAU) {
                    cnt[r] += 1;
                    mn[r] = min(mn[r], code);
                }
            }
        }
    }

    // ---- merge across the 16 lanes of each row-group (order-invariant) ----
#pragma unroll
    for (int mask = 1; mask < 16; mask <<= 1) {
#pragma unroll
        for (int r = 0; r < 4; ++r) {
            mx[r]  = fmaxf(mx[r], __shfl_xor(mx[r], mask));
            cnt[r] += __shfl_xor(cnt[r], mask);
            mn[r]  = min(mn[r], __shfl_xor(mn[r], mask));
        }
    }
    if ((l & 15) == 0) {
#pragma unroll
        for (int r = 0; r < 4; ++r) {
            const int p = p0 + (l >> 4) * 4 + r;
            if (cnt[r] == 1) {
                ids[p] = mn[r];
                out[IDX_OFF + n0 + p] = (float)mn[r];
            } else {
                need[p] = 1;
            }
        }
    }

    // ---- wave-local exact fallback (bit-exact numpy chain; rare) ----
    for (int pp = 0; pp < 16; ++pp) {
        const int p = p0 + pp;
        if (!need[p]) continue;             // uniform within wave
        // A_np(p): every lane computes identically (uniform LDS reads)
        float xr[D];
#pragma unroll
        for (int d = 0; d < D; ++d) xr[d] = x_lds[d][p];
        const float Anp = np_sumsq64(xr);
        ull_t best = ~0ull;
#pragma unroll
        for (int h = 0; h < 8; ++h) {
            const int k = l + h * 64;
            float acc = 0.f;
#pragma unroll
            for (int d = 0; d < D; ++d)
                acc = __builtin_fmaf(xr[d], cb[k * D + d], acc);
            const float dist = __fsub_rn(__fadd_rn(Anp, e2_lds[k]), 2.0f * acc);
            const ull_t key = ((ull_t)f2ord(dist) << 32) | (ull_t)k;
            if (key < best) best = key;     // ties -> lower k (key low bits)
        }
#pragma unroll
        for (int mask = 1; mask < 64; mask <<= 1) {
            const ull_t o = shfl_xor_u64(best, mask);
            if (o < best) best = o;
        }
        if (l == 0) {
            const int kwin = (int)(best & 0xffffffffull);
            ids[p] = kwin;
            out[IDX_OFF + n0 + p] = (float)kwin;
        }
    }
    __syncthreads();

    // ---- E1: cooperative coalesced gather of chosen rows -> q_lds ----
#pragma unroll
    for (int pb = 0; pb < 64; pb += 4) {
        const int p = pb + w;               // wave w gathers point pb+w
        q_lds[l][p] = cb[ids[p] * D + l];   // one 256B contiguous row read
    }
    __syncthreads();

    // ---- E2: out = fl(x + fl(q - x)) coalesced, loss partials ----
    float* ob = out + b * DHW + hw0;
    float lsum = 0.f;
#pragma unroll
    for (int i = 0; i < 16; ++i) {
        const int d  = w * 16 + i;
        const float xv   = x_lds[d][l];
        const float q    = q_lds[d][l];
        const float diff = __fsub_rn(q, xv);
        lsum = __builtin_fmaf(diff, diff, lsum);
        ob[d * HW + l] = __fadd_rn(xv, diff);
    }
#pragma unroll
    for (int off = 32; off > 0; off >>= 1) lsum += __shfl_down(lsum, off);
    if (l == 0) wsum[w] = lsum;
    __syncthreads();
    if (t == 0)
        partial[blockIdx.x] = __fadd_rn(__fadd_rn(wsum[0], wsum[1]),
                                        __fadd_rn(wsum[2], wsum[3]));
}

// ---------------------------------------------------------------------------
// Loss kernel: reduce 1024 block partials -> loss = 1.25 * MSE
// ---------------------------------------------------------------------------
__global__ void vq_loss_kernel(const float* __restrict__ partial,
                               float* __restrict__ out) {
    __shared__ float sh[256];
    float s = 0.f;
#pragma unroll
    for (int i = 0; i < NBLOCKS / 256; ++i)
        s += partial[threadIdx.x + i * 256];
    sh[threadIdx.x] = s;
    __syncthreads();
    for (int off = 128; off > 0; off >>= 1) {
        if (threadIdx.x < off) sh[threadIdx.x] += sh[threadIdx.x + off];
        __syncthreads();
    }
    if (threadIdx.x == 0)
        out[LOSS_OFF] = 1.25f * sh[0] / (float)OUT_ELEMS;
}

extern "C" void kernel_launch(void* const* d_in, const int* in_sizes, int n_in,
                              void* d_out, int out_size, void* d_ws,
                              size_t ws_size, hipStream_t stream) {
    const float* z  = (const float*)d_in[0];   // [64, 64, 32, 32] f32
    const float* cb = (const float*)d_in[1];   // [512, 64] f32
    float* out = (float*)d_out;
    float* wsf = (float*)d_ws;
    float* e2      = wsf;                      // 512 f32
    float* partial = wsf + 512;                // 1024 f32
    uint4* bhi     = (uint4*)(wsf + 2048);     // 4096 uint4 = 64KB
    uint4* blo     = bhi + 4096;               // 64KB

    vq_prep_kernel<<<8, 64, 0, stream>>>(cb, e2, bhi, blo);
    vq_main_kernel<<<NBLOCKS, 256, 0, stream>>>(z, cb, e2, bhi, blo, out, partial);
    vq_loss_kernel<<<1, 256, 0, stream>>>(partial, out);
}

// Round 11
// 110.345 us; speedup vs baseline: 15.0429x; 15.0429x over previous
//
#include <hip/hip_runtime.h>
#include <hip/hip_bf16.h>
#include <float.h>

#define D 64
#define K 512
#define HW 1024
#define DHW (D * HW)
#define N_PTS 65536
#define OUT_ELEMS (64 * D * HW)     /* 4,194,304 */
#define LOSS_OFF OUT_ELEMS
#define IDX_OFF (OUT_ELEMS + 1)
#define PTS_PER_BLOCK 64
#define NBLOCKS (N_PTS / PTS_PER_BLOCK)   /* 1024 */
#define TAU 4.0e-5f   /* covers numpy fp32 quant slack (~1.2e-5 in score
                         space) + MFMA path error (~1e-6), 3x margin */

typedef unsigned short ushort_t;
typedef unsigned long long ull_t;
typedef __attribute__((ext_vector_type(8))) short bf16x8;
typedef __attribute__((ext_vector_type(4))) float f32x4;

union U16x8 { uint4 u; bf16x8 v; ushort_t s[8]; };

__device__ __forceinline__ ushort_t f2bf(float v) {
    __hip_bfloat16 h = __float2bfloat16(v);
    return *reinterpret_cast<ushort_t*>(&h);
}
__device__ __forceinline__ float bf2f(ushort_t u) {
    unsigned int x = ((unsigned int)u) << 16;
    return *reinterpret_cast<float*>(&x);
}
__device__ __forceinline__ unsigned int f2ord(float s) {
    unsigned int u = __float_as_uint(s);
    return (u & 0x80000000u) ? ~u : (u | 0x80000000u);
}
__device__ __forceinline__ ull_t shfl_xor_u64(ull_t v, int mask) {
    unsigned int lo = (unsigned int)v, hi = (unsigned int)(v >> 32);
    lo = __shfl_xor((int)lo, mask);
    hi = __shfl_xor((int)hi, mask);
    return ((ull_t)hi << 32) | (ull_t)lo;
}

// ---------------------------------------------------------------------------
// numpy pairwise-sum (n=64): 8 accumulators over squares, combined
// ((r0+r1)+(r2+r3))+((r4+r5)+(r6+r7)); all adds/muls un-contracted.
// ---------------------------------------------------------------------------
__device__ __forceinline__ float np_sumsq64(const float* v) {
    float r[8];
#pragma unroll
    for (int j = 0; j < 8; ++j) r[j] = __fmul_rn(v[j], v[j]);
#pragma unroll
    for (int i = 8; i < D; i += 8) {
#pragma unroll
        for (int j = 0; j < 8; ++j)
            r[j] = __fadd_rn(r[j], __fmul_rn(v[i + j], v[i + j]));
    }
    return __fadd_rn(
        __fadd_rn(__fadd_rn(r[0], r[1]), __fadd_rn(r[2], r[3])),
        __fadd_rn(__fadd_rn(r[4], r[5]), __fadd_rn(r[6], r[7])));
}

// ---------------------------------------------------------------------------
// Prep (8 blocks x 64): thread = code k. e2 (numpy order), bhi/blo fragments
// (layout verified r6): idx = kh*2048 + (k>>4)*64 + g*16 + (k&15).
// ---------------------------------------------------------------------------
__global__ void vq_prep_kernel(const float* __restrict__ cb,
                               float* __restrict__ e2,
                               uint4* __restrict__ bhi,
                               uint4* __restrict__ blo) {
    const int k = blockIdx.x * 64 + threadIdx.x;
    float row[D];
#pragma unroll
    for (int d = 0; d < D; ++d) row[d] = cb[k * D + d];
    e2[k] = np_sumsq64(row);
#pragma unroll
    for (int kh = 0; kh < 2; ++kh) {
#pragma unroll
        for (int g = 0; g < 4; ++g) {
            U16x8 hi, lo;
#pragma unroll
            for (int i = 0; i < 8; ++i) {
                float v = row[kh * 32 + g * 8 + i];
                ushort_t h = f2bf(v);
                hi.s[i] = h;
                lo.s[i] = f2bf(__fsub_rn(v, bf2f(h)));
            }
            const int gid = kh * 2048 + (k >> 4) * 64 + g * 16 + (k & 15);
            bhi[gid] = hi.u;
            blo[gid] = lo.u;
        }
    }
}

// ---------------------------------------------------------------------------
// Main VQ: MFMA filter (3 passes) + deterministic online top-2 + wave-local
// exact fallback. Block = 64 points, 4 waves; wave w: points [(w>>1)*32,+32),
// code half w&1 (r7's proven geometry: VGPR fits under launch_bounds(256,2);
// r10 post-mortem: (256,4) + xr[64] spilled to scratch -> 850 MB traffic).
// Per-lane (s1, c1, s2) online tracking: exact-tie sets s2=s1 (gap 0 ->
// fallback); merges are order-invariant; no atomics -> bit-deterministic.
// Gap > TAU -> argmax is provably the numpy argmin; else exact numpy chain
// (validated r2-r10) over all 512 codes, min-key reduced.
// ---------------------------------------------------------------------------
__global__ __launch_bounds__(256, 2) void vq_main_kernel(
        const float* __restrict__ z, const float* __restrict__ cb,
        const float* __restrict__ e2, const uint4* __restrict__ bhi,
        const uint4* __restrict__ blo, float* __restrict__ out,
        float* __restrict__ partial) {
    __shared__ float x_lds[D][65];          // pad 65: conflict-free
    __shared__ float q_lds[D][65];          // gathered codebook rows
    __shared__ float e2_lds[K];
    __shared__ float t2s1[64][2];           // cross-wave top-2 merge
    __shared__ float t2s2[64][2];
    __shared__ int   t2c1[64][2];
    __shared__ int   ids[64];
    __shared__ int   need[64];
    __shared__ float wsum[4];

    const int t     = threadIdx.x;
    const int l     = t & 63;
    const int w     = t >> 6;
    const int chalf = w & 1;
    const int p0    = (w >> 1) * 32;
    const int n0    = blockIdx.x * PTS_PER_BLOCK;
    const int b     = n0 >> 10;
    const int hw0   = n0 & 1023;

    // ---- stage x (coalesced), e2 ----
    const float* zb = z + b * DHW + hw0;
#pragma unroll
    for (int i = 0; i < 16; ++i) {
        const int d = w * 16 + i;
        x_lds[d][l] = zb[d * HW + l];
    }
    e2_lds[t]       = e2[t];
    e2_lds[t + 256] = e2[t + 256];
    __syncthreads();

    // ---- A fragments (hi + exact lo residual), layout verified r6 ----
    bf16x8 ah[2][2], al[2][2];
#pragma unroll
    for (int Mt = 0; Mt < 2; ++Mt) {
#pragma unroll
        for (int kh = 0; kh < 2; ++kh) {
            const int pt = p0 + Mt * 16 + (l & 15);
            const int d0 = kh * 32 + ((l >> 4) << 3);
            U16x8 uh, ul;
#pragma unroll
            for (int i = 0; i < 8; ++i) {
                float v = x_lds[d0 + i][pt];
                ushort_t h = f2bf(v);
                uh.s[i] = h;
                ul.s[i] = f2bf(__fsub_rn(v, bf2f(h)));
            }
            ah[Mt][kh] = uh.v;
            al[Mt][kh] = ul.v;
        }
    }

    // ---- MFMA: C = (xh+xl).eh + xh.el ; B coalesced from global (L2-hot) --
    f32x4 c[2][16];
#pragma unroll
    for (int Mt = 0; Mt < 2; ++Mt)
#pragma unroll
        for (int nt = 0; nt < 16; ++nt) c[Mt][nt] = (f32x4){0.f, 0.f, 0.f, 0.f};

#pragma unroll
    for (int kh = 0; kh < 2; ++kh) {
#pragma unroll
        for (int ntL = 0; ntL < 16; ++ntL) {
            U16x8 bu;
            bu.u = bhi[kh * 2048 + (chalf * 16 + ntL) * 64 + l];
            c[0][ntL] = __builtin_amdgcn_mfma_f32_16x16x32_bf16(ah[0][kh], bu.v, c[0][ntL], 0, 0, 0);
            c[1][ntL] = __builtin_amdgcn_mfma_f32_16x16x32_bf16(ah[1][kh], bu.v, c[1][ntL], 0, 0, 0);
            c[0][ntL] = __builtin_amdgcn_mfma_f32_16x16x32_bf16(al[0][kh], bu.v, c[0][ntL], 0, 0, 0);
            c[1][ntL] = __builtin_amdgcn_mfma_f32_16x16x32_bf16(al[1][kh], bu.v, c[1][ntL], 0, 0, 0);
        }
    }
#pragma unroll
    for (int kh = 0; kh < 2; ++kh) {
#pragma unroll
        for (int ntL = 0; ntL < 16; ++ntL) {
            U16x8 bl;
            bl.u = blo[kh * 2048 + (chalf * 16 + ntL) * 64 + l];
            c[0][ntL] = __builtin_amdgcn_mfma_f32_16x16x32_bf16(ah[0][kh], bl.v, c[0][ntL], 0, 0, 0);
            c[1][ntL] = __builtin_amdgcn_mfma_f32_16x16x32_bf16(ah[1][kh], bl.v, c[1][ntL], 0, 0, 0);
        }
    }

    // ---- online top-2 per (Mt, r): score = C - 0.5*||e||^2 ----
    float s1[2][4], s2[2][4];
    int   c1[2][4];
#pragma unroll
    for (int Mt = 0; Mt < 2; ++Mt)
#pragma unroll
        for (int r = 0; r < 4; ++r) {
            s1[Mt][r] = -FLT_MAX; s2[Mt][r] = -FLT_MAX; c1[Mt][r] = 0x7fffffff;
        }
#pragma unroll
    for (int ntL = 0; ntL < 16; ++ntL) {
        const int code = chalf * 256 + ntL * 16 + (l & 15);
        const float B = e2_lds[code];
#pragma unroll
        for (int Mt = 0; Mt < 2; ++Mt)
#pragma unroll
            for (int r = 0; r < 4; ++r) {
                const float s = __builtin_fmaf(B, -0.5f, c[Mt][ntL][r]);
                if (s > s1[Mt][r]) {
                    s2[Mt][r] = s1[Mt][r]; s1[Mt][r] = s; c1[Mt][r] = code;
                } else if (s == s1[Mt][r]) {
                    c1[Mt][r] = min(c1[Mt][r], code);
                    s2[Mt][r] = s1[Mt][r];      // exact tie -> force fallback
                } else if (s > s2[Mt][r]) {
                    s2[Mt][r] = s;
                }
            }
    }

    // ---- order-invariant butterfly merge over the 16-lane code groups ----
#pragma unroll
    for (int mask = 1; mask < 16; mask <<= 1) {
#pragma unroll
        for (int Mt = 0; Mt < 2; ++Mt)
#pragma unroll
            for (int r = 0; r < 4; ++r) {
                const float os1 = __shfl_xor(s1[Mt][r], mask);
                const float os2 = __shfl_xor(s2[Mt][r], mask);
                const int   oc1 = __shfl_xor(c1[Mt][r], mask);
                if (os1 > s1[Mt][r]) {
                    s2[Mt][r] = fmaxf(s1[Mt][r], os2);
                    s1[Mt][r] = os1; c1[Mt][r] = oc1;
                } else if (os1 == s1[Mt][r]) {
                    c1[Mt][r] = min(c1[Mt][r], oc1);
                    s2[Mt][r] = s1[Mt][r];      // cross-lane tie -> fallback
                } else {
                    s2[Mt][r] = fmaxf(s2[Mt][r], os1);
                }
            }
    }
    if ((l & 15) == 0) {
#pragma unroll
        for (int Mt = 0; Mt < 2; ++Mt)
#pragma unroll
            for (int r = 0; r < 4; ++r) {
                const int p = p0 + Mt * 16 + (l >> 4) * 4 + r;
                t2s1[p][chalf] = s1[Mt][r];
                t2s2[p][chalf] = s2[Mt][r];
                t2c1[p][chalf] = c1[Mt][r];
            }
    }
    __syncthreads();

    // ---- decision (t<64): merge the two code halves, gap test ----
    if (t < 64) {
        float a1 = t2s1[t][0], a2 = t2s2[t][0];
        int   ac = t2c1[t][0];
        const float b1 = t2s1[t][1], b2 = t2s2[t][1];
        const int   bc = t2c1[t][1];
        if (b1 > a1)       { a2 = fmaxf(a1, b2); a1 = b1; ac = bc; }
        else if (b1 == a1) { ac = min(ac, bc); a2 = a1; }
        else               { a2 = fmaxf(a2, b1); }
        if (a1 - a2 > TAU) {
            ids[t] = ac;
            out[IDX_OFF + n0 + t] = (float)ac;
            need[t] = 0;
        } else {
            need[t] = 1;
        }
    }
    __syncthreads();

    // ---- wave-local exact fallback (bit-exact numpy chain; ~1.5% pts) ----
    // wave w owns points [w*16, w*16+16); x read straight from LDS (uniform
    // addresses -> broadcast; NO register array -> no spill, r10 lesson).
    for (int pp = 0; pp < 16; ++pp) {
        const int p = w * 16 + pp;
        if (!need[p]) continue;             // uniform within wave
        float r8[8];
#pragma unroll
        for (int j = 0; j < 8; ++j) {
            const float v = x_lds[j][p];
            r8[j] = __fmul_rn(v, v);
        }
#pragma unroll
        for (int d = 8; d < D; ++d) {
            const float v = x_lds[d][p];
            r8[d & 7] = __fadd_rn(r8[d & 7], __fmul_rn(v, v));
        }
        const float Anp = __fadd_rn(
            __fadd_rn(__fadd_rn(r8[0], r8[1]), __fadd_rn(r8[2], r8[3])),
            __fadd_rn(__fadd_rn(r8[4], r8[5]), __fadd_rn(r8[6], r8[7])));
        ull_t best = ~0ull;
#pragma unroll
        for (int h = 0; h < 8; ++h) {
            const int k = l + h * 64;
            float acc = 0.f;
#pragma unroll
            for (int d = 0; d < D; ++d)
                acc = __builtin_fmaf(x_lds[d][p], cb[k * D + d], acc);
            const float dist = __fsub_rn(__fadd_rn(Anp, e2_lds[k]), 2.0f * acc);
            const ull_t key = ((ull_t)f2ord(dist) << 32) | (ull_t)k;
            if (key < best) best = key;     // ties -> lower k
        }
#pragma unroll
        for (int mask = 1; mask < 64; mask <<= 1) {
            const ull_t o = shfl_xor_u64(best, mask);
            if (o < best) best = o;
        }
        if (l == 0) {
            const int kwin = (int)(best & 0xffffffffull);
            ids[p] = kwin;
            out[IDX_OFF + n0 + p] = (float)kwin;
        }
    }
    __syncthreads();

    // ---- E1: cooperative coalesced gather of chosen rows -> q_lds ----
#pragma unroll
    for (int pb = 0; pb < 64; pb += 4) {
        const int p = pb + w;               // wave w gathers point pb+w
        q_lds[l][p] = cb[ids[p] * D + l];   // one 256B contiguous row read
    }
    __syncthreads();

    // ---- E2: out = fl(x + fl(q - x)) coalesced, loss partials ----
    float* ob = out + b * DHW + hw0;
    float lsum = 0.f;
#pragma unroll
    for (int i = 0; i < 16; ++i) {
        const int d  = w * 16 + i;
        const float xv   = x_lds[d][l];
        const float q    = q_lds[d][l];
        const float diff = __fsub_rn(q, xv);
        lsum = __builtin_fmaf(diff, diff, lsum);
        ob[d * HW + l] = __fadd_rn(xv, diff);
    }
#pragma unroll
    for (int off = 32; off > 0; off >>= 1) lsum += __shfl_down(lsum, off);
    if (l == 0) wsum[w] = lsum;
    __syncthreads();
    if (t == 0)
        partial[blockIdx.x] = __fadd_rn(__fadd_rn(wsum[0], wsum[1]),
                                        __fadd_rn(wsum[2], wsum[3]));
}

// ---------------------------------------------------------------------------
// Loss kernel: reduce 1024 block partials -> loss = 1.25 * MSE
// ---------------------------------------------------------------------------
__global__ void vq_loss_kernel(const float* __restrict__ partial,
                               float* __restrict__ out) {
    __shared__ float sh[256];
    float s = 0.f;
#pragma unroll
    for (int i = 0; i < NBLOCKS / 256; ++i)
        s += partial[threadIdx.x + i * 256];
    sh[threadIdx.x] = s;
    __syncthreads();
    for (int off = 128; off > 0; off >>= 1) {
        if (threadIdx.x < off) sh[threadIdx.x] += sh[threadIdx.x + off];
        __syncthreads();
    }
    if (threadIdx.x == 0)
        out[LOSS_OFF] = 1.25f * sh[0] / (float)OUT_ELEMS;
}

extern "C" void kernel_launch(void* const* d_in, const int* in_sizes, int n_in,
                              void* d_out, int out_size, void* d_ws,
                              size_t ws_size, hipStream_t stream) {
    const float* z  = (const float*)d_in[0];   // [64, 64, 32, 32] f32
    const float* cb = (const float*)d_in[1];   // [512, 64] f32
    float* out = (float*)d_out;
    float* wsf = (float*)d_ws;
    float* e2      = wsf;                      // 512 f32
    float* partial = wsf + 512;                // 1024 f32
    uint4* bhi     = (uint4*)(wsf + 2048);     // 4096 uint4 = 64KB
    uint4* blo     = bhi + 4096;               // 64KB

    vq_prep_kernel<<<8, 64, 0, stream>>>(cb, e2, bhi, blo);
    vq_main_kernel<<<NBLOCKS, 256, 0, stream>>>(z, cb, e2, bhi, blo, out, partial);
    vq_loss_kernel<<<1, 256, 0, stream>>>(partial, out);
}